// Round 9
// baseline (349.694 us; speedup 1.0000x reference)
//
#include <hip/hip_runtime.h>
#include <stdint.h>

#define N_NODES 10000
#define N_EDGES 160000
#define D 512
#define TOT (N_NODES * D)          // 5,120,000
#define MASK_DW (TOT / 32)         // 160,000 dwords per layer
#define FM 16                      // rows per fused-layer block (10000/16 = 625, exact)
#define LDAF 520                   // LDS stride in halves (1040 B)

#define HIST_B 625                 // 160000/256
#define MASK_B 1250                // 2*MASK_DW/256
#define WCV_B  192                 // 8*8*3
#define FILL_B 625
#define DROP_B 5000                // TOT/4/256

typedef _Float16 h8 __attribute__((ext_vector_type(8)));
typedef float f4 __attribute__((ext_vector_type(4)));

// ---------------- threefry2x32 (JAX partitionable semantics) ----------------
__host__ __device__ inline uint32_t rotl32(uint32_t v, int r) {
    return (v << r) | (v >> (32 - r));
}

__host__ __device__ inline void tf2x32(uint32_t k0, uint32_t k1,
                                       uint32_t& x0, uint32_t& x1) {
    uint32_t k2 = k0 ^ k1 ^ 0x1BD11BDAu;
    x0 += k0; x1 += k1;
    x0 += x1; x1 = rotl32(x1, 13); x1 ^= x0;
    x0 += x1; x1 = rotl32(x1, 15); x1 ^= x0;
    x0 += x1; x1 = rotl32(x1, 26); x1 ^= x0;
    x0 += x1; x1 = rotl32(x1,  6); x1 ^= x0;
    x0 += k1; x1 += k2 + 1u;
    x0 += x1; x1 = rotl32(x1, 17); x1 ^= x0;
    x0 += x1; x1 = rotl32(x1, 29); x1 ^= x0;
    x0 += x1; x1 = rotl32(x1, 16); x1 ^= x0;
    x0 += x1; x1 = rotl32(x1, 24); x1 ^= x0;
    x0 += k2; x1 += k0 + 2u;
    x0 += x1; x1 = rotl32(x1, 13); x1 ^= x0;
    x0 += x1; x1 = rotl32(x1, 15); x1 ^= x0;
    x0 += x1; x1 = rotl32(x1, 26); x1 ^= x0;
    x0 += x1; x1 = rotl32(x1,  6); x1 ^= x0;
    x0 += k0; x1 += k1 + 3u;
    x0 += x1; x1 = rotl32(x1, 17); x1 ^= x0;
    x0 += x1; x1 = rotl32(x1, 29); x1 ^= x0;
    x0 += x1; x1 = rotl32(x1, 16); x1 ^= x0;
    x0 += x1; x1 = rotl32(x1, 24); x1 ^= x0;
    x0 += k1; x1 += k2 + 4u;
    x0 += x1; x1 = rotl32(x1, 13); x1 ^= x0;
    x0 += x1; x1 = rotl32(x1, 15); x1 ^= x0;
    x0 += x1; x1 = rotl32(x1, 26); x1 ^= x0;
    x0 += x1; x1 = rotl32(x1,  6); x1 ^= x0;
    x0 += k2; x1 += k0 + 5u;
}

__device__ __forceinline__ float dropout_gate(uint32_t k0, uint32_t k1, uint32_t j) {
    uint32_t c0 = 0u, c1 = j;
    tf2x32(k0, k1, c0, c1);
    uint32_t bits = c0 ^ c1;
    float u = __uint_as_float((bits >> 9) | 0x3f800000u) - 1.0f;
    return (u < 0.8f) ? 1.0f : 0.0f;
}

// ---------------- setup1: hist + dropout-bitmask + W transpose (fused) ------
__global__ __launch_bounds__(256)
void setup1_kernel(const int* __restrict__ src, const int* __restrict__ dst,
                   int* __restrict__ deg_out, int* __restrict__ deg_in,
                   uint32_t* __restrict__ mask,
                   uint32_t k0a, uint32_t k1a, uint32_t k0b, uint32_t k1b,
                   const float* __restrict__ W0, const float* __restrict__ W1,
                   const float* __restrict__ W2, _Float16* __restrict__ Wt) {
    __shared__ float tile[64][65];
    int b = blockIdx.x;
    int tid = threadIdx.x;
    if (b < HIST_B) {
        // degree histogram
        int e = b * 256 + tid;
        if (e < N_EDGES) {
            atomicAdd(&deg_out[src[e]], 1);
            atomicAdd(&deg_in[dst[e]], 1);
        }
    } else if (b < HIST_B + MASK_B) {
        // dropout bitmask for layers 1,2 (pure function of keys)
        int t = (b - HIST_B) * 256 + tid;          // [0, 2*MASK_DW)
        int layer = (t >= MASK_DW) ? 1 : 0;
        uint32_t k0 = layer ? k0b : k0a;
        uint32_t k1 = layer ? k1b : k1a;
        uint32_t base = (uint32_t)(layer ? t - MASK_DW : t) * 32u;
        uint32_t m = 0;
#pragma unroll
        for (int i = 0; i < 32; ++i) {
            uint32_t c0 = 0u, c1 = base + (uint32_t)i;
            tf2x32(k0, k1, c0, c1);
            uint32_t bits = c0 ^ c1;
            float u = __uint_as_float((bits >> 9) | 0x3f800000u) - 1.0f;
            m |= (u < 0.8f ? 1u : 0u) << i;
        }
        mask[t] = m;
    } else {
        // W fp32 [K][N] -> Wt fp16 [N][K], 64x64 LDS tile transpose
        int q = b - (HIST_B + MASK_B);             // [0, 192)
        int bz = q >> 6, r = q & 63;
        int by = r >> 3, bx = r & 7;
        const float* W = (bz == 0) ? W0 : (bz == 1) ? W1 : W2;
        _Float16* T = Wt + (size_t)bz * 512 * 512;
        int r0 = by * 64, c0 = bx * 64;
        int c = tid & 63, rq = tid >> 6;
#pragma unroll
        for (int i = 0; i < 16; ++i) {
            int rr = rq + i * 4;
            tile[rr][c] = W[(size_t)(r0 + rr) * 512 + c0 + c];
        }
        __syncthreads();
        int k = tid & 63, nq = tid >> 6;
#pragma unroll
        for (int i = 0; i < 16; ++i) {
            int n = nq + i * 4;
            T[(size_t)(c0 + n) * 512 + r0 + k] = (_Float16)tile[k][n];
        }
    }
}

// ---------------- scan: single pass, 10 nodes/thread, 2 barriers ------------
__global__ __launch_bounds__(1024)
void scan_kernel(const int* __restrict__ deg_in, const int* __restrict__ deg_out,
                 int* __restrict__ row_ptr,
                 float* __restrict__ rn_in, float* __restrict__ rn_out) {
    __shared__ int wsum[16];
    int tid = threadIdx.x;
    int lane = tid & 63, wv = tid >> 6;
    int base = tid * 10;
    bool act = base < N_NODES;                     // threads 0..999 active
    int d[10];
#pragma unroll
    for (int j = 0; j < 10; ++j) d[j] = 0;
    if (act) {
#pragma unroll
        for (int j = 0; j < 10; ++j) d[j] = deg_in[base + j];
    }
    int tot = 0;
#pragma unroll
    for (int j = 0; j < 10; ++j) tot += d[j];
    int s = tot;
#pragma unroll
    for (int off = 1; off < 64; off <<= 1) {
        int u = __shfl_up(s, off, 64);
        if (lane >= off) s += u;
    }
    if (lane == 63) wsum[wv] = s;
    __syncthreads();
    if (wv == 0 && lane < 16) {
        int ws = wsum[lane];
#pragma unroll
        for (int off = 1; off < 16; off <<= 1) {
            int u = __shfl_up(ws, off, 64);
            if (lane >= off) ws += u;
        }
        wsum[lane] = ws;
    }
    __syncthreads();
    if (act) {
        int run = ((wv > 0) ? wsum[wv - 1] : 0) + (s - tot);
#pragma unroll
        for (int j = 0; j < 10; ++j) {
            int i = base + j;
            row_ptr[i] = run;
            int v = d[j];
            rn_in[i]  = 1.0f / sqrtf(fmaxf((float)v, 1.0f));
            rn_out[i] = 1.0f / sqrtf(fmaxf((float)deg_out[i], 1.0f));
            run += v;
        }
    }
    if (tid == 0) row_ptr[N_NODES] = wsum[15];
}

// ---------------- setup2: CSR fill + input dropout (fused) ------------------
__global__ __launch_bounds__(256)
void setup2_kernel(const int* __restrict__ src, const int* __restrict__ dst,
                   const float* __restrict__ ew, const int* __restrict__ row_ptr,
                   int* __restrict__ cursor, int2* __restrict__ csr,
                   const float* __restrict__ x, _Float16* __restrict__ y,
                   const float* __restrict__ rn_out, uint32_t k0, uint32_t k1) {
    int b = blockIdx.x;
    int tid = threadIdx.x;
    if (b < FILL_B) {
        int e = b * 256 + tid;
        if (e < N_EDGES) {
            int v = dst[e];
            int pos = atomicAdd(&cursor[v], 1);
            csr[row_ptr[v] + pos] = make_int2(src[e], __float_as_int(ew[e]));
        }
    } else {
        int t = (b - FILL_B) * 256 + tid;
        int j = t * 4;
        if (j < TOT) {
            float4 xv = *(const float4*)&x[j];
            float w = rn_out[j >> 9];
            _Float16 r[4];
            uint32_t jj = (uint32_t)j;
#pragma unroll
            for (int i = 0; i < 4; ++i) {
                float g = dropout_gate(k0, k1, jj + (uint32_t)i);
                float xi = (&xv.x)[i];
                r[i] = (_Float16)(g * (xi / 0.8f) * w);
            }
            *(ushort4*)&y[j] = *(ushort4*)r;
        }
    }
}

// ---------------- fused layer: aggregate -> LDS panel -> barrier-free GEMM --
// Block: 16 output rows x 512 cols, 256 threads (4 waves). Grid = 625 (exact).
// Phase 1: wave w aggregates nodes row0+4w..row0+4w+3 (fp32 regs, identical
//          edge order) -> fp16 rows in As (stride 520 halves; bank-uniform).
// Phase 2: barrier-free K-loop: A frags from resident LDS, B frags direct
//          from L2-resident Wt. Wave w owns cols [w*128, w*128+128).
// Epilogue: *rn_in + bias; mode 0: ELU + bitmask dropout + rn_out -> yout fp16
//           mode 1: plain -> fout fp32.  yin != yout (ping-pong, WAR-safe).
__global__ __launch_bounds__(256)
void layer_kernel(const _Float16* __restrict__ yin, const int* __restrict__ row_ptr,
                  const int2* __restrict__ csr, const _Float16* __restrict__ Wt,
                  const float* __restrict__ bias, const float* __restrict__ rn_in,
                  const float* __restrict__ rn_out, const uint32_t* __restrict__ mask,
                  _Float16* __restrict__ yout, float* __restrict__ fout, int mode) {
    __shared__ _Float16 As[FM * LDAF];   // 16.6 KB
    int tid = threadIdx.x;
    int wv = tid >> 6, lane = tid & 63;
    int row0 = blockIdx.x * FM;

    // ---- phase 1: aggregate (4 nodes per wave) ----
#pragma unroll 1
    for (int nn = 0; nn < 4; ++nn) {
        int ln = wv * 4 + nn;            // local row 0..15
        int node = row0 + ln;            // < 10000 always (grid exact)
        float acc[8] = {0, 0, 0, 0, 0, 0, 0, 0};
        int beg = row_ptr[node], end = row_ptr[node + 1];
        int k = beg;
        for (; k + 7 < end; k += 8) {
            h8 a[8];
            float w[8];
#pragma unroll
            for (int q = 0; q < 8; ++q) {
                int2 e = csr[k + q];
                a[q] = *(const h8*)&yin[(size_t)e.x * 512 + lane * 8];
                w[q] = __int_as_float(e.y);
            }
#pragma unroll
            for (int q = 0; q < 8; ++q)
#pragma unroll
                for (int i = 0; i < 8; ++i) acc[i] += w[q] * (float)a[q][i];
        }
        for (; k + 3 < end; k += 4) {
            h8 a[4];
            float w[4];
#pragma unroll
            for (int q = 0; q < 4; ++q) {
                int2 e = csr[k + q];
                a[q] = *(const h8*)&yin[(size_t)e.x * 512 + lane * 8];
                w[q] = __int_as_float(e.y);
            }
#pragma unroll
            for (int q = 0; q < 4; ++q)
#pragma unroll
                for (int i = 0; i < 8; ++i) acc[i] += w[q] * (float)a[q][i];
        }
        for (; k < end; ++k) {
            int2 e0 = csr[k];
            float w0 = __int_as_float(e0.y);
            h8 a = *(const h8*)&yin[(size_t)e0.x * 512 + lane * 8];
#pragma unroll
            for (int i = 0; i < 8; ++i) acc[i] += w0 * (float)a[i];
        }
        _Float16 r[8];
#pragma unroll
        for (int i = 0; i < 8; ++i) r[i] = (_Float16)acc[i];
        *(h8*)&As[ln * LDAF + lane * 8] = *(h8*)r;
    }
    __syncthreads();

    // ---- phase 2: GEMM, wave wv owns cols [wv*128, wv*128+128) ----
    f4 acc[8];
#pragma unroll
    for (int i = 0; i < 8; ++i) acc[i] = (f4){0.f, 0.f, 0.f, 0.f};

    int kf = (lane >> 4) * 8;
    const _Float16* fa = &As[(lane & 15) * LDAF + kf];
    int col0 = wv * 128;
    const _Float16* gB = Wt + (size_t)(col0 + (lane & 15)) * 512 + kf;

#pragma unroll 2
    for (int kk = 0; kk < 512; kk += 32) {
        h8 af = *(const h8*)(fa + kk);
        h8 bf[8];
#pragma unroll
        for (int nt = 0; nt < 8; ++nt)
            bf[nt] = *(const h8*)(gB + (size_t)nt * 16 * 512 + kk);
#pragma unroll
        for (int nt = 0; nt < 8; ++nt)
            acc[nt] = __builtin_amdgcn_mfma_f32_16x16x32_f16(af, bf[nt],
                                                             acc[nt], 0, 0, 0);
    }

    // ---- epilogue. C/D layout: col = lane&15, row = (lane>>4)*4 + reg ----
    int gr0 = row0 + (lane >> 4) * 4;
#pragma unroll
    for (int nt = 0; nt < 8; ++nt) {
        int gc = col0 + nt * 16 + (lane & 15);
        float bcol = bias[gc];
#pragma unroll
        for (int i = 0; i < 4; ++i) {
            int gr = gr0 + i;
            float v = acc[nt][i] * rn_in[gr] + bcol;
            if (mode == 0) {
                v = (v > 0.f) ? v : expm1f(v);
                uint32_t m = mask[gr * 16 + (gc >> 5)];
                float keep = (float)((m >> (gc & 31)) & 1u);
                v = keep * (v / 0.8f) * rn_out[gr];
                yout[(size_t)gr * 512 + gc] = (_Float16)v;
            } else {
                fout[(size_t)gr * 512 + gc] = v;
            }
        }
    }
}

// ---------------- launch ----------------
extern "C" void kernel_launch(void* const* d_in, const int* in_sizes, int n_in,
                              void* d_out, int out_size, void* d_ws, size_t ws_size,
                              hipStream_t stream) {
    const float* h   = (const float*)d_in[0];
    const int*   src = (const int*)d_in[1];
    const int*   dst = (const int*)d_in[2];
    const float* ew  = (const float*)d_in[3];
    const float* W0  = (const float*)d_in[4];
    const float* b0  = (const float*)d_in[5];
    const float* W1  = (const float*)d_in[6];
    const float* b1  = (const float*)d_in[7];
    const float* W2  = (const float*)d_in[8];
    const float* b2  = (const float*)d_in[9];
    const float* bl[3] = {b0, b1, b2};
    float* out = (float*)d_out;

    char* ws = (char*)d_ws;
    _Float16* yA   = (_Float16*)ws; ws += (size_t)TOT * 2;            // 10.24 MB
    _Float16* yB   = (_Float16*)ws; ws += (size_t)TOT * 2;            // 10.24 MB
    _Float16* Wt   = (_Float16*)ws; ws += (size_t)3 * 512 * 512 * 2;  // 1.57 MB
    uint32_t* mask = (uint32_t*)ws; ws += (size_t)2 * MASK_DW * 4;    // 1.28 MB
    // the next three must stay contiguous: zeroed with ONE memset
    int* degi_in  = (int*)ws;  ws += N_NODES * 4;
    int* degi_out = (int*)ws;  ws += N_NODES * 4;
    int* cursor   = (int*)ws;  ws += N_NODES * 4;
    int* row_ptr  = (int*)ws;  ws += (N_NODES + 1) * 4;
    ws = (char*)(((uintptr_t)ws + 15) & ~(uintptr_t)15);
    int2* csr     = (int2*)ws; ws += (size_t)N_EDGES * 8;
    float* rn_in  = (float*)ws; ws += N_NODES * 4;
    float* rn_out = (float*)ws; ws += N_NODES * 4;

    hipMemsetAsync(degi_in, 0, 3 * N_NODES * 4, stream);

    // partitionable split: subkey i = both lanes of cipher(key=(0,42), x0=0, x1=i)
    uint32_t dk[3][2];
    for (int i = 0; i < 3; ++i) {
        uint32_t c0 = 0u, c1 = (uint32_t)i;
        tf2x32(0u, 42u, c0, c1);
        dk[i][0] = c0; dk[i][1] = c1;
    }

    setup1_kernel<<<HIST_B + MASK_B + WCV_B, 256, 0, stream>>>(
        src, dst, degi_out, degi_in, mask,
        dk[1][0], dk[1][1], dk[2][0], dk[2][1], W0, W1, W2, Wt);
    scan_kernel<<<1, 1024, 0, stream>>>(degi_in, degi_out, row_ptr, rn_in, rn_out);
    setup2_kernel<<<FILL_B + DROP_B, 256, 0, stream>>>(
        src, dst, ew, row_ptr, cursor, csr, h, yA, rn_out, dk[0][0], dk[0][1]);

    // ping-pong: yA -> yB -> yA -> out
    const int NBLK = N_NODES / FM;   // 625, exact
    layer_kernel<<<NBLK, 256, 0, stream>>>(yA, row_ptr, csr, Wt, bl[0],
                                           rn_in, rn_out, mask, yB, out, 0);
    layer_kernel<<<NBLK, 256, 0, stream>>>(yB, row_ptr, csr, Wt + (size_t)512 * 512,
                                           bl[1], rn_in, rn_out, mask + MASK_DW,
                                           yA, out, 0);
    layer_kernel<<<NBLK, 256, 0, stream>>>(yA, row_ptr, csr, Wt + (size_t)2 * 512 * 512,
                                           bl[2], rn_in, rn_out, nullptr,
                                           nullptr, out, 1);
}

// Round 10
// 332.793 us; speedup vs baseline: 1.0508x; 1.0508x over previous
//
#include <hip/hip_runtime.h>
#include <stdint.h>

#define N_NODES 10000
#define N_EDGES 160000
#define D 512
#define TOT (N_NODES * D)          // 5,120,000
#define MASK_DW (TOT / 32)         // 160,000 dwords per layer
#define FM 32                      // rows per fused-layer block
#define NBLK 313                   // ceil(10000/32)
#define LDAF 520                   // LDS stride in halves (1040 B)

#define HIST_B 625                 // 160000/256
#define MASK_B 1250                // 2*MASK_DW/256
#define WCV_B  192                 // 8*8*3
#define FILL_B 625
#define DROP_B 5000                // TOT/4/256

typedef _Float16 h8 __attribute__((ext_vector_type(8)));
typedef float f4 __attribute__((ext_vector_type(4)));

// ---------------- threefry2x32 (JAX partitionable semantics) ----------------
__host__ __device__ inline uint32_t rotl32(uint32_t v, int r) {
    return (v << r) | (v >> (32 - r));
}

__host__ __device__ inline void tf2x32(uint32_t k0, uint32_t k1,
                                       uint32_t& x0, uint32_t& x1) {
    uint32_t k2 = k0 ^ k1 ^ 0x1BD11BDAu;
    x0 += k0; x1 += k1;
    x0 += x1; x1 = rotl32(x1, 13); x1 ^= x0;
    x0 += x1; x1 = rotl32(x1, 15); x1 ^= x0;
    x0 += x1; x1 = rotl32(x1, 26); x1 ^= x0;
    x0 += x1; x1 = rotl32(x1,  6); x1 ^= x0;
    x0 += k1; x1 += k2 + 1u;
    x0 += x1; x1 = rotl32(x1, 17); x1 ^= x0;
    x0 += x1; x1 = rotl32(x1, 29); x1 ^= x0;
    x0 += x1; x1 = rotl32(x1, 16); x1 ^= x0;
    x0 += x1; x1 = rotl32(x1, 24); x1 ^= x0;
    x0 += k2; x1 += k0 + 2u;
    x0 += x1; x1 = rotl32(x1, 13); x1 ^= x0;
    x0 += x1; x1 = rotl32(x1, 15); x1 ^= x0;
    x0 += x1; x1 = rotl32(x1, 26); x1 ^= x0;
    x0 += x1; x1 = rotl32(x1,  6); x1 ^= x0;
    x0 += k0; x1 += k1 + 3u;
    x0 += x1; x1 = rotl32(x1, 17); x1 ^= x0;
    x0 += x1; x1 = rotl32(x1, 29); x1 ^= x0;
    x0 += x1; x1 = rotl32(x1, 16); x1 ^= x0;
    x0 += x1; x1 = rotl32(x1, 24); x1 ^= x0;
    x0 += k1; x1 += k2 + 4u;
    x0 += x1; x1 = rotl32(x1, 13); x1 ^= x0;
    x0 += x1; x1 = rotl32(x1, 15); x1 ^= x0;
    x0 += x1; x1 = rotl32(x1, 26); x1 ^= x0;
    x0 += x1; x1 = rotl32(x1,  6); x1 ^= x0;
    x0 += k2; x1 += k0 + 5u;
}

__device__ __forceinline__ float dropout_gate(uint32_t k0, uint32_t k1, uint32_t j) {
    uint32_t c0 = 0u, c1 = j;
    tf2x32(k0, k1, c0, c1);
    uint32_t bits = c0 ^ c1;
    float u = __uint_as_float((bits >> 9) | 0x3f800000u) - 1.0f;
    return (u < 0.8f) ? 1.0f : 0.0f;
}

// ---------------- setup1: hist + dropout-bitmask + W transpose (fused) ------
__global__ __launch_bounds__(256)
void setup1_kernel(const int* __restrict__ src, const int* __restrict__ dst,
                   int* __restrict__ deg_out, int* __restrict__ deg_in,
                   uint32_t* __restrict__ mask,
                   uint32_t k0a, uint32_t k1a, uint32_t k0b, uint32_t k1b,
                   const float* __restrict__ W0, const float* __restrict__ W1,
                   const float* __restrict__ W2, _Float16* __restrict__ Wt) {
    __shared__ float tile[64][65];
    int b = blockIdx.x;
    int tid = threadIdx.x;
    if (b < HIST_B) {
        int e = b * 256 + tid;
        if (e < N_EDGES) {
            atomicAdd(&deg_out[src[e]], 1);
            atomicAdd(&deg_in[dst[e]], 1);
        }
    } else if (b < HIST_B + MASK_B) {
        int t = (b - HIST_B) * 256 + tid;          // [0, 2*MASK_DW)
        int layer = (t >= MASK_DW) ? 1 : 0;
        uint32_t k0 = layer ? k0b : k0a;
        uint32_t k1 = layer ? k1b : k1a;
        uint32_t base = (uint32_t)(layer ? t - MASK_DW : t) * 32u;
        uint32_t m = 0;
#pragma unroll
        for (int i = 0; i < 32; ++i) {
            uint32_t c0 = 0u, c1 = base + (uint32_t)i;
            tf2x32(k0, k1, c0, c1);
            uint32_t bits = c0 ^ c1;
            float u = __uint_as_float((bits >> 9) | 0x3f800000u) - 1.0f;
            m |= (u < 0.8f ? 1u : 0u) << i;
        }
        mask[t] = m;
    } else {
        int q = b - (HIST_B + MASK_B);             // [0, 192)
        int bz = q >> 6, r = q & 63;
        int by = r >> 3, bx = r & 7;
        const float* W = (bz == 0) ? W0 : (bz == 1) ? W1 : W2;
        _Float16* T = Wt + (size_t)bz * 512 * 512;
        int r0 = by * 64, c0 = bx * 64;
        int c = tid & 63, rq = tid >> 6;
#pragma unroll
        for (int i = 0; i < 16; ++i) {
            int rr = rq + i * 4;
            tile[rr][c] = W[(size_t)(r0 + rr) * 512 + c0 + c];
        }
        __syncthreads();
        int k = tid & 63, nq = tid >> 6;
#pragma unroll
        for (int i = 0; i < 16; ++i) {
            int n = nq + i * 4;
            T[(size_t)(c0 + n) * 512 + r0 + k] = (_Float16)tile[k][n];
        }
    }
}

// ---------------- scan: single pass, 10 nodes/thread, 2 barriers ------------
__global__ __launch_bounds__(1024)
void scan_kernel(const int* __restrict__ deg_in, const int* __restrict__ deg_out,
                 int* __restrict__ row_ptr,
                 float* __restrict__ rn_in, float* __restrict__ rn_out) {
    __shared__ int wsum[16];
    int tid = threadIdx.x;
    int lane = tid & 63, wv = tid >> 6;
    int base = tid * 10;
    bool act = base < N_NODES;
    int d[10];
#pragma unroll
    for (int j = 0; j < 10; ++j) d[j] = 0;
    if (act) {
#pragma unroll
        for (int j = 0; j < 10; ++j) d[j] = deg_in[base + j];
    }
    int tot = 0;
#pragma unroll
    for (int j = 0; j < 10; ++j) tot += d[j];
    int s = tot;
#pragma unroll
    for (int off = 1; off < 64; off <<= 1) {
        int u = __shfl_up(s, off, 64);
        if (lane >= off) s += u;
    }
    if (lane == 63) wsum[wv] = s;
    __syncthreads();
    if (wv == 0 && lane < 16) {
        int ws = wsum[lane];
#pragma unroll
        for (int off = 1; off < 16; off <<= 1) {
            int u = __shfl_up(ws, off, 64);
            if (lane >= off) ws += u;
        }
        wsum[lane] = ws;
    }
    __syncthreads();
    if (act) {
        int run = ((wv > 0) ? wsum[wv - 1] : 0) + (s - tot);
#pragma unroll
        for (int j = 0; j < 10; ++j) {
            int i = base + j;
            row_ptr[i] = run;
            int v = d[j];
            rn_in[i]  = 1.0f / sqrtf(fmaxf((float)v, 1.0f));
            rn_out[i] = 1.0f / sqrtf(fmaxf((float)deg_out[i], 1.0f));
            run += v;
        }
    }
    if (tid == 0) row_ptr[N_NODES] = wsum[15];
}

// ---------------- setup2: CSR fill + input dropout (fused) ------------------
__global__ __launch_bounds__(256)
void setup2_kernel(const int* __restrict__ src, const int* __restrict__ dst,
                   const float* __restrict__ ew, const int* __restrict__ row_ptr,
                   int* __restrict__ cursor, int2* __restrict__ csr,
                   const float* __restrict__ x, _Float16* __restrict__ y,
                   const float* __restrict__ rn_out, uint32_t k0, uint32_t k1) {
    int b = blockIdx.x;
    int tid = threadIdx.x;
    if (b < FILL_B) {
        int e = b * 256 + tid;
        if (e < N_EDGES) {
            int v = dst[e];
            int pos = atomicAdd(&cursor[v], 1);
            csr[row_ptr[v] + pos] = make_int2(src[e], __float_as_int(ew[e]));
        }
    } else {
        int t = (b - FILL_B) * 256 + tid;
        int j = t * 4;
        if (j < TOT) {
            float4 xv = *(const float4*)&x[j];
            float w = rn_out[j >> 9];
            _Float16 r[4];
            uint32_t jj = (uint32_t)j;
#pragma unroll
            for (int i = 0; i < 4; ++i) {
                float g = dropout_gate(k0, k1, jj + (uint32_t)i);
                float xi = (&xv.x)[i];
                r[i] = (_Float16)(g * (xi / 0.8f) * w);
            }
            *(ushort4*)&y[j] = *(ushort4*)r;
        }
    }
}

// ---------------- fused layer: aggregate -> LDS panel -> barrier-free GEMM --
// Block: 32 output rows x 512 cols, 1024 threads (16 waves). Grid = 313.
// Phase 1: wave w aggregates nodes row0+2w, row0+2w+1 (fp32 regs, identical
//          edge order) -> fp16 rows in LDS panel (stride 520 halves).
// Phase 2: barrier-free K-loop: A frags from resident LDS (2 M-tiles),
//          B frags direct from L2-resident Wt; wave owns 32 cols (r8's
//          proven width). 4 MFMA per K-step per wave.
// Epilogue: *rn_in + bias; mode 0: ELU + bitmask dropout + rn_out -> yout fp16
//           mode 1: plain -> fout fp32.  yin != yout (ping-pong, WAR-safe).
__global__ __launch_bounds__(1024)
void layer_kernel(const _Float16* __restrict__ yin, const int* __restrict__ row_ptr,
                  const int2* __restrict__ csr, const _Float16* __restrict__ Wt,
                  const float* __restrict__ bias, const float* __restrict__ rn_in,
                  const float* __restrict__ rn_out, const uint32_t* __restrict__ mask,
                  _Float16* __restrict__ yout, float* __restrict__ fout, int mode) {
    __shared__ _Float16 As[FM * LDAF];   // 33.3 KB
    int tid = threadIdx.x;
    int wv = tid >> 6, lane = tid & 63;
    int row0 = blockIdx.x * FM;

    // ---- phase 1: aggregate (2 nodes per wave) ----
#pragma unroll 1
    for (int nn = 0; nn < 2; ++nn) {
        int ln = wv * 2 + nn;            // local row 0..31
        int node = row0 + ln;
        float acc[8] = {0, 0, 0, 0, 0, 0, 0, 0};
        if (node < N_NODES) {
            int beg = row_ptr[node], end = row_ptr[node + 1];
            int k = beg;
            for (; k + 7 < end; k += 8) {
                h8 a[8];
                float w[8];
#pragma unroll
                for (int q = 0; q < 8; ++q) {
                    int2 e = csr[k + q];
                    a[q] = *(const h8*)&yin[(size_t)e.x * 512 + lane * 8];
                    w[q] = __int_as_float(e.y);
                }
#pragma unroll
                for (int q = 0; q < 8; ++q)
#pragma unroll
                    for (int i = 0; i < 8; ++i) acc[i] += w[q] * (float)a[q][i];
            }
            for (; k + 3 < end; k += 4) {
                h8 a[4];
                float w[4];
#pragma unroll
                for (int q = 0; q < 4; ++q) {
                    int2 e = csr[k + q];
                    a[q] = *(const h8*)&yin[(size_t)e.x * 512 + lane * 8];
                    w[q] = __int_as_float(e.y);
                }
#pragma unroll
                for (int q = 0; q < 4; ++q)
#pragma unroll
                    for (int i = 0; i < 8; ++i) acc[i] += w[q] * (float)a[q][i];
            }
            for (; k < end; ++k) {
                int2 e0 = csr[k];
                float w0 = __int_as_float(e0.y);
                h8 a = *(const h8*)&yin[(size_t)e0.x * 512 + lane * 8];
#pragma unroll
                for (int i = 0; i < 8; ++i) acc[i] += w0 * (float)a[i];
            }
        }
        _Float16 r[8];
#pragma unroll
        for (int i = 0; i < 8; ++i) r[i] = (_Float16)acc[i];
        *(h8*)&As[ln * LDAF + lane * 8] = *(h8*)r;
    }
    __syncthreads();

    // ---- phase 2: GEMM, wave wv owns cols [wv*32, wv*32+32), rows all 32 ----
    f4 acc[2][2];
#pragma unroll
    for (int i = 0; i < 2; ++i)
#pragma unroll
        for (int j = 0; j < 2; ++j) acc[i][j] = (f4){0.f, 0.f, 0.f, 0.f};

    int kf = (lane >> 4) * 8;
    const _Float16* fa = &As[(lane & 15) * LDAF + kf];
    int col0 = wv * 32;
    const _Float16* gB0 = Wt + (size_t)(col0 + (lane & 15)) * 512 + kf;
    const _Float16* gB1 = gB0 + (size_t)16 * 512;

#pragma unroll 4
    for (int kk = 0; kk < 512; kk += 32) {
        h8 af0 = *(const h8*)(fa + kk);
        h8 af1 = *(const h8*)(fa + 16 * LDAF + kk);
        h8 bf0 = *(const h8*)(gB0 + kk);
        h8 bf1 = *(const h8*)(gB1 + kk);
        acc[0][0] = __builtin_amdgcn_mfma_f32_16x16x32_f16(af0, bf0, acc[0][0], 0, 0, 0);
        acc[0][1] = __builtin_amdgcn_mfma_f32_16x16x32_f16(af0, bf1, acc[0][1], 0, 0, 0);
        acc[1][0] = __builtin_amdgcn_mfma_f32_16x16x32_f16(af1, bf0, acc[1][0], 0, 0, 0);
        acc[1][1] = __builtin_amdgcn_mfma_f32_16x16x32_f16(af1, bf1, acc[1][1], 0, 0, 0);
    }

    // ---- epilogue. C/D layout: col = lane&15, row = (lane>>4)*4 + reg ----
#pragma unroll
    for (int mt = 0; mt < 2; ++mt) {
#pragma unroll
        for (int nt = 0; nt < 2; ++nt) {
            int gr0 = row0 + mt * 16 + (lane >> 4) * 4;
            int gc = col0 + nt * 16 + (lane & 15);
            float bcol = bias[gc];
#pragma unroll
            for (int i = 0; i < 4; ++i) {
                int gr = gr0 + i;
                if (gr >= N_NODES) continue;
                float v = acc[mt][nt][i] * rn_in[gr] + bcol;
                if (mode == 0) {
                    v = (v > 0.f) ? v : expm1f(v);
                    uint32_t m = mask[gr * 16 + (gc >> 5)];
                    float keep = (float)((m >> (gc & 31)) & 1u);
                    v = keep * (v / 0.8f) * rn_out[gr];
                    yout[(size_t)gr * 512 + gc] = (_Float16)v;
                } else {
                    fout[(size_t)gr * 512 + gc] = v;
                }
            }
        }
    }
}

// ---------------- launch ----------------
extern "C" void kernel_launch(void* const* d_in, const int* in_sizes, int n_in,
                              void* d_out, int out_size, void* d_ws, size_t ws_size,
                              hipStream_t stream) {
    const float* h   = (const float*)d_in[0];
    const int*   src = (const int*)d_in[1];
    const int*   dst = (const int*)d_in[2];
    const float* ew  = (const float*)d_in[3];
    const float* W0  = (const float*)d_in[4];
    const float* b0  = (const float*)d_in[5];
    const float* W1  = (const float*)d_in[6];
    const float* b1  = (const float*)d_in[7];
    const float* W2  = (const float*)d_in[8];
    const float* b2  = (const float*)d_in[9];
    const float* bl[3] = {b0, b1, b2};
    float* out = (float*)d_out;

    char* ws = (char*)d_ws;
    _Float16* yA   = (_Float16*)ws; ws += (size_t)TOT * 2;            // 10.24 MB
    _Float16* yB   = (_Float16*)ws; ws += (size_t)TOT * 2;            // 10.24 MB
    _Float16* Wt   = (_Float16*)ws; ws += (size_t)3 * 512 * 512 * 2;  // 1.57 MB
    uint32_t* mask = (uint32_t*)ws; ws += (size_t)2 * MASK_DW * 4;    // 1.28 MB
    // the next three must stay contiguous: zeroed with ONE memset
    int* degi_in  = (int*)ws;  ws += N_NODES * 4;
    int* degi_out = (int*)ws;  ws += N_NODES * 4;
    int* cursor   = (int*)ws;  ws += N_NODES * 4;
    int* row_ptr  = (int*)ws;  ws += (N_NODES + 1) * 4;
    ws = (char*)(((uintptr_t)ws + 15) & ~(uintptr_t)15);
    int2* csr     = (int2*)ws; ws += (size_t)N_EDGES * 8;
    float* rn_in  = (float*)ws; ws += N_NODES * 4;
    float* rn_out = (float*)ws; ws += N_NODES * 4;

    hipMemsetAsync(degi_in, 0, 3 * N_NODES * 4, stream);

    // partitionable split: subkey i = both lanes of cipher(key=(0,42), x0=0, x1=i)
    uint32_t dk[3][2];
    for (int i = 0; i < 3; ++i) {
        uint32_t c0 = 0u, c1 = (uint32_t)i;
        tf2x32(0u, 42u, c0, c1);
        dk[i][0] = c0; dk[i][1] = c1;
    }

    setup1_kernel<<<HIST_B + MASK_B + WCV_B, 256, 0, stream>>>(
        src, dst, degi_out, degi_in, mask,
        dk[1][0], dk[1][1], dk[2][0], dk[2][1], W0, W1, W2, Wt);
    scan_kernel<<<1, 1024, 0, stream>>>(degi_in, degi_out, row_ptr, rn_in, rn_out);
    setup2_kernel<<<FILL_B + DROP_B, 256, 0, stream>>>(
        src, dst, ew, row_ptr, cursor, csr, h, yA, rn_out, dk[0][0], dk[0][1]);

    // ping-pong: yA -> yB -> yA -> out
    layer_kernel<<<NBLK, 1024, 0, stream>>>(yA, row_ptr, csr, Wt, bl[0],
                                            rn_in, rn_out, mask, yB, out, 0);
    layer_kernel<<<NBLK, 1024, 0, stream>>>(yB, row_ptr, csr, Wt + (size_t)512 * 512,
                                            bl[1], rn_in, rn_out, mask + MASK_DW,
                                            yA, out, 0);
    layer_kernel<<<NBLK, 1024, 0, stream>>>(yA, row_ptr, csr, Wt + (size_t)2 * 512 * 512,
                                            bl[2], rn_in, rn_out, nullptr,
                                            nullptr, out, 1);
}